// Round 6
// baseline (210.614 us; speedup 1.0000x reference)
//
#include <hip/hip_runtime.h>

// CapsuleOut: B=256, O=10, R=1152, I=8, D=16, 3 routing iterations.
// Single kernel. Block = (o, b-pair), 384 threads, XCD-swizzled grid of 1280.
//  - W[o] streamed through DOUBLE-BUFFERED LDS (2 x 24KB, 48 rows/chunk) via
//    __builtin_amdgcn_global_load_lds (16B/lane, no VGPR round-trip). Loads for
//    chunk c+1 issued BEFORE consume(c); the barrier's implicit vmcnt(0)
//    drains them -> latency hides under compute; ONE barrier per chunk.
//  - LDS bank-swizzle via pre-swizzled GLOBAL source (linear LDS dest),
//    read back with the same XOR (involution): f4idx ^ (row&7).
//  - ZERO thread-local arrays: prior fragments are named structs (F4x4),
//    inputs are named float4s, logits named floats. (Rounds 3/4 lost ~60MB
//    of HBM to a 64B/thread scratch line: WRITE_SIZE == blocks*threads*64B.)
//  - No token-pasting macros (round-5 compile failure: P##0q0.x lexes 0q0.x
//    as one pp-number). Struct refs + forceinline functions instead.
//  - Routing: softmax w/o max-subtraction (logits bounded ~+-30), DPP 16-lane
//    reductions + 34-thread cross-group pass (validated rounds 3-4).

#define BB 256
#define OO 10
#define RR 1152
#define II 8
#define DD 16
#define NITER 3
#define NT 384
#define NB 2
#define CH 48                    // rows per chunk
#define NCH (RR / CH)            // 24 chunks
#define GRID (OO * BB / NB)      // 1280, divisible by 8
#define NGRP (NT / 16)           // 24 sixteen-lane groups

// ---- 16-lane in-register reduction: VALU-pipe only (DPP) ----
template<int CTRL>
__device__ __forceinline__ float dpp_add(float x) {
    int p = __builtin_amdgcn_update_dpp(0, __float_as_int(x), CTRL, 0xF, 0xF, true);
    return x + __int_as_float(p);
}
__device__ __forceinline__ float red16(float x) {
    x = dpp_add<0xB1>(x);    // quad_perm(1,0,3,2)
    x = dpp_add<0x4E>(x);    // quad_perm(2,3,0,1)
    x = dpp_add<0x124>(x);   // row_ror:4
    x = dpp_add<0x128>(x);   // row_ror:8
    return x;                // every lane holds its 16-lane-group sum
}
__device__ __forceinline__ float4 fma4(float4 w, float a, float4 c) {
    c.x = fmaf(w.x, a, c.x); c.y = fmaf(w.y, a, c.y);
    c.z = fmaf(w.z, a, c.z); c.w = fmaf(w.w, a, c.w);
    return c;
}
__device__ __forceinline__ float dot4(float4 a, float4 b) {
    return fmaf(a.x, b.x, fmaf(a.y, b.y, fmaf(a.z, b.z, a.w * b.w)));
}
__device__ __forceinline__ void gload_lds16(const void* g, void* l) {
    __builtin_amdgcn_global_load_lds(
        (const __attribute__((address_space(1))) void*)g,
        (__attribute__((address_space(3))) void*)l, 16, 0, 0);
}

// prior fragment: one (batch,k) = 16 floats as 4 named float4s (SROA-safe)
struct F4x4 { float4 q0, q1, q2, q3; };

__device__ __forceinline__ void mks(const F4x4& p0, const F4x4& p1, const F4x4& p2,
                                    float e0, float e1, float e2,
                                    float4& s0, float4& s1, float4& s2, float4& s3) {
    s0.x = red16(fmaf(e0, p0.q0.x, fmaf(e1, p1.q0.x, e2 * p2.q0.x)));
    s0.y = red16(fmaf(e0, p0.q0.y, fmaf(e1, p1.q0.y, e2 * p2.q0.y)));
    s0.z = red16(fmaf(e0, p0.q0.z, fmaf(e1, p1.q0.z, e2 * p2.q0.z)));
    s0.w = red16(fmaf(e0, p0.q0.w, fmaf(e1, p1.q0.w, e2 * p2.q0.w)));
    s1.x = red16(fmaf(e0, p0.q1.x, fmaf(e1, p1.q1.x, e2 * p2.q1.x)));
    s1.y = red16(fmaf(e0, p0.q1.y, fmaf(e1, p1.q1.y, e2 * p2.q1.y)));
    s1.z = red16(fmaf(e0, p0.q1.z, fmaf(e1, p1.q1.z, e2 * p2.q1.z)));
    s1.w = red16(fmaf(e0, p0.q1.w, fmaf(e1, p1.q1.w, e2 * p2.q1.w)));
    s2.x = red16(fmaf(e0, p0.q2.x, fmaf(e1, p1.q2.x, e2 * p2.q2.x)));
    s2.y = red16(fmaf(e0, p0.q2.y, fmaf(e1, p1.q2.y, e2 * p2.q2.y)));
    s2.z = red16(fmaf(e0, p0.q2.z, fmaf(e1, p1.q2.z, e2 * p2.q2.z)));
    s2.w = red16(fmaf(e0, p0.q2.w, fmaf(e1, p1.q2.w, e2 * p2.q2.w)));
    s3.x = red16(fmaf(e0, p0.q3.x, fmaf(e1, p1.q3.x, e2 * p2.q3.x)));
    s3.y = red16(fmaf(e0, p0.q3.y, fmaf(e1, p1.q3.y, e2 * p2.q3.y)));
    s3.z = red16(fmaf(e0, p0.q3.z, fmaf(e1, p1.q3.z, e2 * p2.q3.z)));
    s3.w = red16(fmaf(e0, p0.q3.w, fmaf(e1, p1.q3.w, e2 * p2.q3.w)));
}
__device__ __forceinline__ float dotF(const F4x4& p, float4 f0, float4 f1,
                                      float4 f2, float4 f3) {
    return dot4(p.q0, f0) + dot4(p.q1, f1) + dot4(p.q2, f2) + dot4(p.q3, f3);
}

__global__ __launch_bounds__(NT, 2) void capsule_one(
    const float* __restrict__ inp,   // [B,R,8]
    const float* __restrict__ W,     // [O,R,128]
    float* __restrict__ out)         // [B,O,16]
{
    __shared__ float4 wbuf[2][CH * 32];          // 2 x 24 KB
    __shared__ float4 red4[NB][NGRP][4];         // per-group s[d] partials
    __shared__ float  redS[NB][NGRP];            // per-group sum(exp)
    __shared__ __align__(16) float finalv[NB][20];

    int wg = blockIdx.x;
    wg = (wg & 7) * (GRID / 8) + (wg >> 3);      // bijective XCD swizzle
    const int o  = wg / (BB / NB);
    const int b0 = (wg % (BB / NB)) * NB;
    const int tid = threadIdx.x;
    const int g  = tid >> 4;
    const int lc = tid & 15;
    const int myphase = tid / CH;                // 0..7
    const int rho     = tid - myphase * CH;      // 0..47
    const int rsw     = rho & 7;
    const unsigned wbase = (unsigned)(tid & ~63); // wave-uniform

    const float4* w4 = reinterpret_cast<const float4*>(W) + (size_t)o * (RR * 32);
    const float4* ip = reinterpret_cast<const float4*>(inp);

    F4x4 pA0{}, pA1{}, pA2{}, pB0{}, pB1{}, pB2{};   // 96 floats, registers
    float lgA0 = 0.f, lgA1 = 0.f, lgA2 = 0.f;
    float lgB0 = 0.f, lgB1 = 0.f, lgB2 = 0.f;
    float4 iA0, iA1, iB0, iB1;                   // inputs for current k

    // stage chunk C into wbuf[C&1]; global source pre-swizzled, LDS linear
#define STAGE(C) do {                                                          \
        const float4* src_ = w4 + (size_t)(C) * (CH * 32);                     \
        char* lb_ = (char*)(&wbuf[(C) & 1][0]);                                \
        { int j_ = 0 * NT + tid; int gs_ = j_ ^ ((j_ >> 5) & 7);               \
          gload_lds16((const void*)(src_ + gs_), (void*)(lb_ + ((0 * NT + wbase) << 4))); } \
        { int j_ = 1 * NT + tid; int gs_ = j_ ^ ((j_ >> 5) & 7);               \
          gload_lds16((const void*)(src_ + gs_), (void*)(lb_ + ((1 * NT + wbase) << 4))); } \
        { int j_ = 2 * NT + tid; int gs_ = j_ ^ ((j_ >> 5) & 7);               \
          gload_lds16((const void*)(src_ + gs_), (void*)(lb_ + ((2 * NT + wbase) << 4))); } \
        { int j_ = 3 * NT + tid; int gs_ = j_ ^ ((j_ >> 5) & 7);               \
          gload_lds16((const void*)(src_ + gs_), (void*)(lb_ + ((3 * NT + wbase) << 4))); } \
    } while (0)

#define LOADIN(K) do {                                                         \
        const size_t rk_ = (size_t)(tid + (K) * NT);                           \
        iA0 = ip[((size_t)b0 * RR + rk_) * 2];                                 \
        iA1 = ip[((size_t)b0 * RR + rk_) * 2 + 1];                             \
        iB0 = ip[((size_t)(b0 + 1) * RR + rk_) * 2];                           \
        iB1 = ip[((size_t)(b0 + 1) * RR + rk_) * 2 + 1];                       \
    } while (0)

    // consume one i-column of my row: PA/PB are F4x4 variables (no pasting)
#define CROW(PA, PB, I, A, B) do {                                             \
        float4 w0_ = rb_[(rho * 32 + (I) * 4 + 0) ^ rsw];                      \
        float4 w1_ = rb_[(rho * 32 + (I) * 4 + 1) ^ rsw];                      \
        float4 w2_ = rb_[(rho * 32 + (I) * 4 + 2) ^ rsw];                      \
        float4 w3_ = rb_[(rho * 32 + (I) * 4 + 3) ^ rsw];                      \
        PA.q0 = fma4(w0_, (A), PA.q0); PB.q0 = fma4(w0_, (B), PB.q0);          \
        PA.q1 = fma4(w1_, (A), PA.q1); PB.q1 = fma4(w1_, (B), PB.q1);          \
        PA.q2 = fma4(w2_, (A), PA.q2); PB.q2 = fma4(w2_, (B), PB.q2);          \
        PA.q3 = fma4(w3_, (A), PA.q3); PB.q3 = fma4(w3_, (B), PB.q3);          \
    } while (0)

#define STEP(C, PA, PB) do {                                                   \
        if ((C) + 1 < NCH) STAGE((C) + 1);                                     \
        if (myphase == ((C) & 7)) {                                            \
            const float4* rb_ = &wbuf[(C) & 1][0];                             \
            CROW(PA, PB, 0, iA0.x, iB0.x); CROW(PA, PB, 1, iA0.y, iB0.y);      \
            CROW(PA, PB, 2, iA0.z, iB0.z); CROW(PA, PB, 3, iA0.w, iB0.w);      \
            CROW(PA, PB, 4, iA1.x, iB1.x); CROW(PA, PB, 5, iA1.y, iB1.y);      \
            CROW(PA, PB, 6, iA1.z, iB1.z); CROW(PA, PB, 7, iA1.w, iB1.w);      \
        }                                                                      \
        __syncthreads();                                                       \
    } while (0)

    // prologue: chunk 0 + inputs k=0
    STAGE(0);
    LOADIN(0);
    __syncthreads();

    STEP(0,  pA0, pB0); STEP(1,  pA0, pB0); STEP(2,  pA0, pB0); STEP(3,  pA0, pB0);
    STEP(4,  pA0, pB0); STEP(5,  pA0, pB0); STEP(6,  pA0, pB0); STEP(7,  pA0, pB0);
    LOADIN(1);
    STEP(8,  pA1, pB1); STEP(9,  pA1, pB1); STEP(10, pA1, pB1); STEP(11, pA1, pB1);
    STEP(12, pA1, pB1); STEP(13, pA1, pB1); STEP(14, pA1, pB1); STEP(15, pA1, pB1);
    LOADIN(2);
    STEP(16, pA2, pB2); STEP(17, pA2, pB2); STEP(18, pA2, pB2); STEP(19, pA2, pB2);
    STEP(20, pA2, pB2); STEP(21, pA2, pB2); STEP(22, pA2, pB2); STEP(23, pA2, pB2);

    // ---- dynamic routing ----
    #pragma unroll
    for (int it = 0; it < NITER; ++it) {
        {   // batch A partials
            const float e0 = __expf(lgA0), e1 = __expf(lgA1), e2 = __expf(lgA2);
            const float Sp = red16(e0 + e1 + e2);
            float4 s0, s1, s2, s3;
            mks(pA0, pA1, pA2, e0, e1, e2, s0, s1, s2, s3);
            if (lc < 4) {
                red4[0][g][lc] = (lc == 0) ? s0 : (lc == 1) ? s1 : (lc == 2) ? s2 : s3;
            } else if (lc == 4) redS[0][g] = Sp;
        }
        {   // batch B partials
            const float e0 = __expf(lgB0), e1 = __expf(lgB1), e2 = __expf(lgB2);
            const float Sp = red16(e0 + e1 + e2);
            float4 s0, s1, s2, s3;
            mks(pB0, pB1, pB2, e0, e1, e2, s0, s1, s2, s3);
            if (lc < 4) {
                red4[1][g][lc] = (lc == 0) ? s0 : (lc == 1) ? s1 : (lc == 2) ? s2 : s3;
            } else if (lc == 4) redS[1][g] = Sp;
        }
        __syncthreads();

        if (tid < 34) {           // cross-group reduce: one value per thread
            const int nb = (tid >= 17) ? 1 : 0;
            const int j = tid - nb * 17;
            float t = 0.f;
            if (j < 16) {
                const float* base = (const float*)red4 + nb * (NGRP * 16) + j;
                #pragma unroll
                for (int gg = 0; gg < NGRP; ++gg) t += base[gg * 16];
            } else {
                #pragma unroll
                for (int gg = 0; gg < NGRP; ++gg) t += redS[nb][gg];
            }
            finalv[nb][j] = t;
        }
        __syncthreads();

        {   // batch A squash + logit update / output
            const float4* fp = reinterpret_cast<const float4*>(&finalv[0][0]);
            const float4 f0 = fp[0], f1 = fp[1], f2 = fp[2], f3 = fp[3];
            const float S = finalv[0][16];
            const float inv = 1.0f / S;
            const float sq = (dot4(f0, f0) + dot4(f1, f1) + dot4(f2, f2) + dot4(f3, f3)) * inv * inv;
            const float F = inv * sqrtf(sq) / (1.0f + sq);   // v[d] = s[d]*F
            if (it < NITER - 1) {
                lgA0 = fmaf(F, dotF(pA0, f0, f1, f2, f3), lgA0);
                lgA1 = fmaf(F, dotF(pA1, f0, f1, f2, f3), lgA1);
                lgA2 = fmaf(F, dotF(pA2, f0, f1, f2, f3), lgA2);
            } else if (tid < DD) {
                out[((size_t)b0 * OO + o) * DD + tid] = finalv[0][tid] * F;
            }
        }
        {   // batch B squash + logit update / output
            const float4* fp = reinterpret_cast<const float4*>(&finalv[1][0]);
            const float4 f0 = fp[0], f1 = fp[1], f2 = fp[2], f3 = fp[3];
            const float S = finalv[1][16];
            const float inv = 1.0f / S;
            const float sq = (dot4(f0, f0) + dot4(f1, f1) + dot4(f2, f2) + dot4(f3, f3)) * inv * inv;
            const float F = inv * sqrtf(sq) / (1.0f + sq);
            if (it < NITER - 1) {
                lgB0 = fmaf(F, dotF(pB0, f0, f1, f2, f3), lgB0);
                lgB1 = fmaf(F, dotF(pB1, f0, f1, f2, f3), lgB1);
                lgB2 = fmaf(F, dotF(pB2, f0, f1, f2, f3), lgB2);
            } else if (tid < DD) {
                out[((size_t)(b0 + 1) * OO + o) * DD + tid] = finalv[1][tid] * F;
            }
        }
    }
}

extern "C" void kernel_launch(void* const* d_in, const int* in_sizes, int n_in,
                              void* d_out, int out_size, void* d_ws, size_t ws_size,
                              hipStream_t stream) {
    const float* inputs = (const float*)d_in[0];
    const float* W = (const float*)d_in[1];
    float* out = (float*)d_out;
    hipLaunchKernelGGL(capsule_one, dim3(GRID), dim3(NT), 0, stream, inputs, W, out);
}

// Round 8
// 153.822 us; speedup vs baseline: 1.3692x; 1.3692x over previous
//
#include <hip/hip_runtime.h>

// CapsuleOut: B=256, O=10, R=1152, I=8, D=16, 3 routing iterations.
// Single kernel, single dispatch, no workspace, no W staging, no transpose.
//
// Decomposition: thread = (rslot = tid>>2 in 0..95, dq = tid&3).
// Thread owns rows {c*96 + rslot, c=0..11}, one d-quad (4 floats) each.
//   W reads: float4 at W[o][row][ii*16 + dq*4], ii=0..7 -> per instruction a
//   wave covers 16 contiguous 64B segments (2 touches/128B line, vs 8 in the
//   round-1 row-gather). All 384 threads active, ZERO barriers in priors.
// Batch A priors (12 f4) + all logits (24 f) in registers (~86 persistent
// floats); batch B priors in thread-private LDS slots (73.7 KB, b128,
// conflict-free, no sync needed). NO __launch_bounds__: empirically it was
// the spill source (rounds 2/3/6: caps 84/84/104 < live state -> 64B/thread
// scratch; WRITE_SIZE == blocks*threads*64B).
// Routing: softmax w/o max-subtraction (|logit| <~ 25, validated r2-r6),
// row-sums via shfl_xor over rslots, d-sums via 2 DPP quad-perm adds over
// the 4 dq lanes, 34-thread cross-wave pass, 2 barriers/iter.

#define BB 256
#define OO 10
#define RR 1152
#define DD 16
#define NITER 3
#define NT 384
#define NB 2
#define GRID (OO * BB / NB)      // 1280, divisible by 8
#define NW 6                     // waves per block

template<int CTRL>
__device__ __forceinline__ float dpp_add(float x) {
    int p = __builtin_amdgcn_update_dpp(0, __float_as_int(x), CTRL, 0xF, 0xF, true);
    return x + __int_as_float(p);
}
// sum over the 4 dq lanes (lane bits 0..1): quad_perm xor1, xor2
__device__ __forceinline__ float red_dq(float x) {
    x = dpp_add<0xB1>(x);
    x = dpp_add<0x4E>(x);
    return x;
}
__device__ __forceinline__ float4 fma4(float4 w, float a, float4 c) {
    c.x = fmaf(w.x, a, c.x); c.y = fmaf(w.y, a, c.y);
    c.z = fmaf(w.z, a, c.z); c.w = fmaf(w.w, a, c.w);
    return c;
}
__device__ __forceinline__ float dot4(float4 a, float4 b) {
    return fmaf(a.x, b.x, fmaf(a.y, b.y, fmaf(a.z, b.z, a.w * b.w)));
}
// reduce over the 16 rslots of a wave (lane bits 2..5)
__device__ __forceinline__ float red_rs(float x) {
    x += __shfl_xor(x, 4);  x += __shfl_xor(x, 8);
    x += __shfl_xor(x, 16); x += __shfl_xor(x, 32);
    return x;
}
__device__ __forceinline__ float4 red_rs4(float4 v) {
    v.x = red_rs(v.x); v.y = red_rs(v.y); v.z = red_rs(v.z); v.w = red_rs(v.w);
    return v;
}

struct F4x4 { float4 q0, q1, q2, q3; };

__global__ void capsule_direct(
    const float* __restrict__ inp,   // [B,R,8]
    const float* __restrict__ W,     // [O,R,128]
    float* __restrict__ out)         // [B,O,16]
{
    __shared__ float4 priB[12 * NT];             // batch-B priors, 73728 B
    __shared__ float4 red4[NB][NW][4];           // per-wave s[d] partials
    __shared__ float  redS[NB][NW];              // per-wave sum(exp)
    __shared__ __align__(16) float finalv[NB][20];

    int wg = blockIdx.x;
    wg = (wg & 7) * (GRID / 8) + (wg >> 3);      // bijective XCD swizzle
    const int o  = wg / (BB / NB);
    const int b0 = (wg % (BB / NB)) * NB;
    const int tid = threadIdx.x;
    const int dq = tid & 3;
    const int rslot = tid >> 2;                  // 0..95
    const int wid = tid >> 6;
    const int lane = tid & 63;

    const float4* w4 = reinterpret_cast<const float4*>(W) + (size_t)o * (RR * 32) + dq;
    const float4* ip = reinterpret_cast<const float4*>(inp);

    F4x4 PAa{}, PAb{}, PAc{};                    // batch-A priors: c=0..3,4..7,8..11
    float4 lgAa{0,0,0,0}, lgAb{0,0,0,0}, lgAc{0,0,0,0};
    float4 lgBa{0,0,0,0}, lgBb{0,0,0,0}, lgBc{0,0,0,0};

    // ---- priors: all threads active, no barriers ----
#define DO_C(C, PACC) do {                                                     \
        const int row_ = (C) * 96 + rslot;                                     \
        const float4 a0_ = ip[((size_t)b0 * RR + row_) * 2];                   \
        const float4 a1_ = ip[((size_t)b0 * RR + row_) * 2 + 1];               \
        const float4 c0_ = ip[((size_t)(b0 + 1) * RR + row_) * 2];             \
        const float4 c1_ = ip[((size_t)(b0 + 1) * RR + row_) * 2 + 1];         \
        const float4* wr_ = w4 + row_ * 32;                                    \
        float4 pb_{0.f, 0.f, 0.f, 0.f};                                        \
        float4 w_;                                                             \
        w_ = wr_[0];  PACC = fma4(w_, a0_.x, PACC); pb_ = fma4(w_, c0_.x, pb_);\
        w_ = wr_[4];  PACC = fma4(w_, a0_.y, PACC); pb_ = fma4(w_, c0_.y, pb_);\
        w_ = wr_[8];  PACC = fma4(w_, a0_.z, PACC); pb_ = fma4(w_, c0_.z, pb_);\
        w_ = wr_[12]; PACC = fma4(w_, a0_.w, PACC); pb_ = fma4(w_, c0_.w, pb_);\
        w_ = wr_[16]; PACC = fma4(w_, a1_.x, PACC); pb_ = fma4(w_, c1_.x, pb_);\
        w_ = wr_[20]; PACC = fma4(w_, a1_.y, PACC); pb_ = fma4(w_, c1_.y, pb_);\
        w_ = wr_[24]; PACC = fma4(w_, a1_.z, PACC); pb_ = fma4(w_, c1_.z, pb_);\
        w_ = wr_[28]; PACC = fma4(w_, a1_.w, PACC); pb_ = fma4(w_, c1_.w, pb_);\
        priB[(C) * NT + tid] = pb_;                                            \
    } while (0)

    DO_C(0,  PAa.q0); DO_C(1,  PAa.q1); DO_C(2,  PAa.q2); DO_C(3,  PAa.q3);
    DO_C(4,  PAb.q0); DO_C(5,  PAb.q1); DO_C(6,  PAb.q2); DO_C(7,  PAb.q3);
    DO_C(8,  PAc.q0); DO_C(9,  PAc.q1); DO_C(10, PAc.q2); DO_C(11, PAc.q3);

    // ---- dynamic routing ----
    #pragma unroll
    for (int it = 0; it < NITER; ++it) {
        // -- batch A partials (registers) --
        {
            float4 ea, eb, ec;
            ea.x = __expf(lgAa.x); ea.y = __expf(lgAa.y);
            ea.z = __expf(lgAa.z); ea.w = __expf(lgAa.w);
            eb.x = __expf(lgAb.x); eb.y = __expf(lgAb.y);
            eb.z = __expf(lgAb.z); eb.w = __expf(lgAb.w);
            ec.x = __expf(lgAc.x); ec.y = __expf(lgAc.y);
            ec.z = __expf(lgAc.z); ec.w = __expf(lgAc.w);
            float Se = ea.x + ea.y + ea.z + ea.w + eb.x + eb.y + eb.z + eb.w
                     + ec.x + ec.y + ec.z + ec.w;
            float4 s4{0.f, 0.f, 0.f, 0.f};
            s4 = fma4(PAa.q0, ea.x, s4); s4 = fma4(PAa.q1, ea.y, s4);
            s4 = fma4(PAa.q2, ea.z, s4); s4 = fma4(PAa.q3, ea.w, s4);
            s4 = fma4(PAb.q0, eb.x, s4); s4 = fma4(PAb.q1, eb.y, s4);
            s4 = fma4(PAb.q2, eb.z, s4); s4 = fma4(PAb.q3, eb.w, s4);
            s4 = fma4(PAc.q0, ec.x, s4); s4 = fma4(PAc.q1, ec.y, s4);
            s4 = fma4(PAc.q2, ec.z, s4); s4 = fma4(PAc.q3, ec.w, s4);
            s4 = red_rs4(s4);            // sum over 16 rslots of this wave
            Se = red_rs(Se);             // ditto (dq lanes identical, xor>=4 only)
            if (lane < 4) red4[0][wid][lane] = s4;   // lane==dq here
            else if (lane == 4) redS[0][wid] = Se;
        }
        // -- batch B partials (priors from thread-private LDS) --
        {
            float4 ea, eb, ec;
            ea.x = __expf(lgBa.x); ea.y = __expf(lgBa.y);
            ea.z = __expf(lgBa.z); ea.w = __expf(lgBa.w);
            eb.x = __expf(lgBb.x); eb.y = __expf(lgBb.y);
            eb.z = __expf(lgBb.z); eb.w = __expf(lgBb.w);
            ec.x = __expf(lgBc.x); ec.y = __expf(lgBc.y);
            ec.z = __expf(lgBc.z); ec.w = __expf(lgBc.w);
            float Se = ea.x + ea.y + ea.z + ea.w + eb.x + eb.y + eb.z + eb.w
                     + ec.x + ec.y + ec.z + ec.w;
            float4 s4{0.f, 0.f, 0.f, 0.f};
            s4 = fma4(priB[0  * NT + tid], ea.x, s4);
            s4 = fma4(priB[1  * NT + tid], ea.y, s4);
            s4 = fma4(priB[2  * NT + tid], ea.z, s4);
            s4 = fma4(priB[3  * NT + tid], ea.w, s4);
            s4 = fma4(priB[4  * NT + tid], eb.x, s4);
            s4 = fma4(priB[5  * NT + tid], eb.y, s4);
            s4 = fma4(priB[6  * NT + tid], eb.z, s4);
            s4 = fma4(priB[7  * NT + tid], eb.w, s4);
            s4 = fma4(priB[8  * NT + tid], ec.x, s4);
            s4 = fma4(priB[9  * NT + tid], ec.y, s4);
            s4 = fma4(priB[10 * NT + tid], ec.z, s4);
            s4 = fma4(priB[11 * NT + tid], ec.w, s4);
            s4 = red_rs4(s4);
            Se = red_rs(Se);
            if (lane < 4) red4[1][wid][lane] = s4;
            else if (lane == 4) redS[1][wid] = Se;
        }
        __syncthreads();

        if (tid < 34) {               // cross-wave reduce: one value per thread
            const int nb = (tid >= 17) ? 1 : 0;
            const int j = tid - nb * 17;
            float t = 0.f;
            if (j < 16) {
                const float* base = (const float*)red4 + nb * (NW * 16) + j;
                #pragma unroll
                for (int w = 0; w < NW; ++w) t += base[w * 16];
            } else {
                #pragma unroll
                for (int w = 0; w < NW; ++w) t += redS[nb][w];
            }
            finalv[nb][j] = t;
        }
        __syncthreads();

        // -- squash + logit update / output, batch A --
        {
            const float4* fp = reinterpret_cast<const float4*>(&finalv[0][0]);
            const float4 f0 = fp[0], f1 = fp[1], f2 = fp[2], f3 = fp[3];
            const float S = finalv[0][16];
            const float inv = 1.0f / S;
            const float sq = (dot4(f0, f0) + dot4(f1, f1) + dot4(f2, f2)
                              + dot4(f3, f3)) * inv * inv;
            const float F = inv * sqrtf(sq) / (1.0f + sq);     // v[d] = s[d]*F
            if (it < NITER - 1) {
                const float4 vq = fp[dq];                      // my d-quad of s
                // delta[row] = F * red_dq( dot4(P_quad, s_quad) )
                lgAa.x = fmaf(F, red_dq(dot4(PAa.q0, vq)), lgAa.x);
                lgAa.y = fmaf(F, red_dq(dot4(PAa.q1, vq)), lgAa.y);
                lgAa.z = fmaf(F, red_dq(dot4(PAa.q2, vq)), lgAa.z);
                lgAa.w = fmaf(F, red_dq(dot4(PAa.q3, vq)), lgAa.w);
                lgAb.x = fmaf(F, red_dq(dot4(PAb.q0, vq)), lgAb.x);
                lgAb.y = fmaf(F, red_dq(dot4(PAb.q1, vq)), lgAb.y);
                lgAb.z = fmaf(F, red_dq(dot4(PAb.q2, vq)), lgAb.z);
                lgAb.w = fmaf(F, red_dq(dot4(PAb.q3, vq)), lgAb.w);
                lgAc.x = fmaf(F, red_dq(dot4(PAc.q0, vq)), lgAc.x);
                lgAc.y = fmaf(F, red_dq(dot4(PAc.q1, vq)), lgAc.y);
                lgAc.z = fmaf(F, red_dq(dot4(PAc.q2, vq)), lgAc.z);
                lgAc.w = fmaf(F, red_dq(dot4(PAc.q3, vq)), lgAc.w);
            } else if (tid < DD) {
                out[((size_t)b0 * OO + o) * DD + tid] = finalv[0][tid] * F;
            }
        }
        // -- squash + logit update / output, batch B --
        {
            const float4* fp = reinterpret_cast<const float4*>(&finalv[1][0]);
            const float4 f0 = fp[0], f1 = fp[1], f2 = fp[2], f3 = fp[3];
            const float S = finalv[1][16];
            const float inv = 1.0f / S;
            const float sq = (dot4(f0, f0) + dot4(f1, f1) + dot4(f2, f2)
                              + dot4(f3, f3)) * inv * inv;
            const float F = inv * sqrtf(sq) / (1.0f + sq);
            if (it < NITER - 1) {
                const float4 vq = fp[dq];
                lgBa.x = fmaf(F, red_dq(dot4(priB[0  * NT + tid], vq)), lgBa.x);
                lgBa.y = fmaf(F, red_dq(dot4(priB[1  * NT + tid], vq)), lgBa.y);
                lgBa.z = fmaf(F, red_dq(dot4(priB[2  * NT + tid], vq)), lgBa.z);
                lgBa.w = fmaf(F, red_dq(dot4(priB[3  * NT + tid], vq)), lgBa.w);
                lgBb.x = fmaf(F, red_dq(dot4(priB[4  * NT + tid], vq)), lgBb.x);
                lgBb.y = fmaf(F, red_dq(dot4(priB[5  * NT + tid], vq)), lgBb.y);
                lgBb.z = fmaf(F, red_dq(dot4(priB[6  * NT + tid], vq)), lgBb.z);
                lgBb.w = fmaf(F, red_dq(dot4(priB[7  * NT + tid], vq)), lgBb.w);
                lgBc.x = fmaf(F, red_dq(dot4(priB[8  * NT + tid], vq)), lgBc.x);
                lgBc.y = fmaf(F, red_dq(dot4(priB[9  * NT + tid], vq)), lgBc.y);
                lgBc.z = fmaf(F, red_dq(dot4(priB[10 * NT + tid], vq)), lgBc.z);
                lgBc.w = fmaf(F, red_dq(dot4(priB[11 * NT + tid], vq)), lgBc.w);
            } else if (tid < DD) {
                out[((size_t)(b0 + 1) * OO + o) * DD + tid] = finalv[1][tid] * F;
            }
        }
    }
}

extern "C" void kernel_launch(void* const* d_in, const int* in_sizes, int n_in,
                              void* d_out, int out_size, void* d_ws, size_t ws_size,
                              hipStream_t stream) {
    const float* inputs = (const float*)d_in[0];
    const float* W = (const float*)d_in[1];
    float* out = (float*)d_out;
    hipLaunchKernelGGL(capsule_direct, dim3(GRID), dim3(NT), 0, stream,
                       inputs, W, out);
}

// Round 9
// 152.127 us; speedup vs baseline: 1.3845x; 1.0111x over previous
//
#include <hip/hip_runtime.h>

// CapsuleOut: B=256, O=10, R=1152, I=8, D=16, 3 routing iterations.
// Round 9: NB=1, zero-spill-by-design.
//   - Empirical VGPR caps on this toolchain: noLB->64, (384,3)->84, (384,2)->104,
//     (384)->96. Only LB(384)+~65 live floats (round 1) never spilled. So:
//     LB(384) and live state sized to ~85 peak (48 prior + 12 logit + temps).
//   - One (b,o) per block, grid 2560 (XCD-swizzled). Thread = (rslot=tid>>2,
//     dq=tid&3): owns rows {c*96+rslot, c=0..11}, d-quad [4dq,4dq+4).
//     W reads: float4 at W[o][row][ii*16+4dq] -> wave covers 16 contiguous
//     64B segments per instruction (validated r8: coalescing fine, spill was
//     the problem). All threads active, zero barriers in priors.
//   - LDS only for reductions (~500B). Routing: softmax w/o max-subtraction
//     (|logit| <~ 25, validated r2-r8), shfl_xor over rslots, DPP quad sums
//     over dq lanes, 17-thread cross-wave pass, 2 barriers/iter.

#define BB 256
#define OO 10
#define RR 1152
#define DD 16
#define NITER 3
#define NT 384
#define GRID (OO * BB)           // 2560, divisible by 8
#define NW 6                     // waves per block

template<int CTRL>
__device__ __forceinline__ float dpp_add(float x) {
    int p = __builtin_amdgcn_update_dpp(0, __float_as_int(x), CTRL, 0xF, 0xF, true);
    return x + __int_as_float(p);
}
// sum over the 4 dq lanes (lane bits 0..1): quad_perm xor1, xor2
__device__ __forceinline__ float red_dq(float x) {
    x = dpp_add<0xB1>(x);
    x = dpp_add<0x4E>(x);
    return x;
}
__device__ __forceinline__ float4 fma4(float4 w, float a, float4 c) {
    c.x = fmaf(w.x, a, c.x); c.y = fmaf(w.y, a, c.y);
    c.z = fmaf(w.z, a, c.z); c.w = fmaf(w.w, a, c.w);
    return c;
}
__device__ __forceinline__ float dot4(float4 a, float4 b) {
    return fmaf(a.x, b.x, fmaf(a.y, b.y, fmaf(a.z, b.z, a.w * b.w)));
}
// reduce over the 16 rslots of a wave (lane bits 2..5)
__device__ __forceinline__ float red_rs(float x) {
    x += __shfl_xor(x, 4);  x += __shfl_xor(x, 8);
    x += __shfl_xor(x, 16); x += __shfl_xor(x, 32);
    return x;
}
__device__ __forceinline__ float4 red_rs4(float4 v) {
    v.x = red_rs(v.x); v.y = red_rs(v.y); v.z = red_rs(v.z); v.w = red_rs(v.w);
    return v;
}

struct F4x4 { float4 q0, q1, q2, q3; };

__global__ __launch_bounds__(NT) void capsule_nb1(
    const float* __restrict__ inp,   // [B,R,8]
    const float* __restrict__ W,     // [O,R,128]
    float* __restrict__ out)         // [B,O,16]
{
    __shared__ float4 red4[NW][4];               // per-wave s[d] partials
    __shared__ float  redS[NW];                  // per-wave sum(exp)
    __shared__ __align__(16) float finalv[20];

    int wg = blockIdx.x;
    wg = (wg & 7) * (GRID / 8) + (wg >> 3);      // bijective XCD swizzle
    const int o = wg / BB;
    const int b = wg % BB;
    const int tid = threadIdx.x;
    const int dq = tid & 3;
    const int rslot = tid >> 2;                  // 0..95
    const int wid = tid >> 6;
    const int lane = tid & 63;

    const float4* w4 = reinterpret_cast<const float4*>(W)
                       + (size_t)o * (RR * 32) + dq;
    const float4* ip = reinterpret_cast<const float4*>(inp) + (size_t)b * (RR * 2);

    F4x4 Pa{}, Pb{}, Pc{};                       // 12 prior quads (48 floats)
    float4 lga{0,0,0,0}, lgb{0,0,0,0}, lgc{0,0,0,0};   // 12 logits

    // ---- priors: all threads active, no barriers ----
#define DO_C(C, PACC) do {                                                     \
        const int row_ = (C) * 96 + rslot;                                     \
        const float4 a0_ = ip[row_ * 2];                                       \
        const float4 a1_ = ip[row_ * 2 + 1];                                   \
        const float4* wr_ = w4 + row_ * 32;                                    \
        float4 w_;                                                             \
        w_ = wr_[0];  PACC = fma4(w_, a0_.x, PACC);                            \
        w_ = wr_[4];  PACC = fma4(w_, a0_.y, PACC);                            \
        w_ = wr_[8];  PACC = fma4(w_, a0_.z, PACC);                            \
        w_ = wr_[12]; PACC = fma4(w_, a0_.w, PACC);                            \
        w_ = wr_[16]; PACC = fma4(w_, a1_.x, PACC);                            \
        w_ = wr_[20]; PACC = fma4(w_, a1_.y, PACC);                            \
        w_ = wr_[24]; PACC = fma4(w_, a1_.z, PACC);                            \
        w_ = wr_[28]; PACC = fma4(w_, a1_.w, PACC);                            \
    } while (0)

    DO_C(0,  Pa.q0); DO_C(1,  Pa.q1); DO_C(2,  Pa.q2); DO_C(3,  Pa.q3);
    DO_C(4,  Pb.q0); DO_C(5,  Pb.q1); DO_C(6,  Pb.q2); DO_C(7,  Pb.q3);
    DO_C(8,  Pc.q0); DO_C(9,  Pc.q1); DO_C(10, Pc.q2); DO_C(11, Pc.q3);

    // ---- dynamic routing ----
    #pragma unroll
    for (int it = 0; it < NITER; ++it) {
        {   // partials: s[d] = sum_r exp(logit_r) * P_r[d], Se = sum_r exp
            float4 ea, eb, ec;
            ea.x = __expf(lga.x); ea.y = __expf(lga.y);
            ea.z = __expf(lga.z); ea.w = __expf(lga.w);
            eb.x = __expf(lgb.x); eb.y = __expf(lgb.y);
            eb.z = __expf(lgb.z); eb.w = __expf(lgb.w);
            ec.x = __expf(lgc.x); ec.y = __expf(lgc.y);
            ec.z = __expf(lgc.z); ec.w = __expf(lgc.w);
            float Se = ea.x + ea.y + ea.z + ea.w + eb.x + eb.y + eb.z + eb.w
                     + ec.x + ec.y + ec.z + ec.w;
            float4 s4{0.f, 0.f, 0.f, 0.f};
            s4 = fma4(Pa.q0, ea.x, s4); s4 = fma4(Pa.q1, ea.y, s4);
            s4 = fma4(Pa.q2, ea.z, s4); s4 = fma4(Pa.q3, ea.w, s4);
            s4 = fma4(Pb.q0, eb.x, s4); s4 = fma4(Pb.q1, eb.y, s4);
            s4 = fma4(Pb.q2, eb.z, s4); s4 = fma4(Pb.q3, eb.w, s4);
            s4 = fma4(Pc.q0, ec.x, s4); s4 = fma4(Pc.q1, ec.y, s4);
            s4 = fma4(Pc.q2, ec.z, s4); s4 = fma4(Pc.q3, ec.w, s4);
            s4 = red_rs4(s4);        // sum over this wave's 16 rslots
            Se = red_rs(Se);         // (dq lanes identical; xor>=4 only)
            if (lane < 4) red4[wid][lane] = s4;      // lane==dq for lanes 0..3
            else if (lane == 4) redS[wid] = Se;
        }
        __syncthreads();

        if (tid < 17) {              // cross-wave reduce: one value per thread
            float t = 0.f;
            if (tid < 16) {
                const float* base = (const float*)red4 + tid;
                #pragma unroll
                for (int w = 0; w < NW; ++w) t += base[w * 16];
            } else {
                #pragma unroll
                for (int w = 0; w < NW; ++w) t += redS[w];
            }
            finalv[tid] = t;
        }
        __syncthreads();

        {   // squash + logit update / output
            const float4* fp = reinterpret_cast<const float4*>(&finalv[0]);
            const float4 f0 = fp[0], f1 = fp[1], f2 = fp[2], f3 = fp[3];
            const float S = finalv[16];
            const float inv = 1.0f / S;
            const float sq = (dot4(f0, f0) + dot4(f1, f1) + dot4(f2, f2)
                              + dot4(f3, f3)) * inv * inv;
            const float F = inv * sqrtf(sq) / (1.0f + sq);     // v[d] = s[d]*F
            if (it < NITER - 1) {
                const float4 vq = fp[dq];                      // my d-quad of s
                // delta[row] = F * red_dq( dot4(P_quad, s_quad) )
                lga.x = fmaf(F, red_dq(dot4(Pa.q0, vq)), lga.x);
                lga.y = fmaf(F, red_dq(dot4(Pa.q1, vq)), lga.y);
                lga.z = fmaf(F, red_dq(dot4(Pa.q2, vq)), lga.z);
                lga.w = fmaf(F, red_dq(dot4(Pa.q3, vq)), lga.w);
                lgb.x = fmaf(F, red_dq(dot4(Pb.q0, vq)), lgb.x);
                lgb.y = fmaf(F, red_dq(dot4(Pb.q1, vq)), lgb.y);
                lgb.z = fmaf(F, red_dq(dot4(Pb.q2, vq)), lgb.z);
                lgb.w = fmaf(F, red_dq(dot4(Pb.q3, vq)), lgb.w);
                lgc.x = fmaf(F, red_dq(dot4(Pc.q0, vq)), lgc.x);
                lgc.y = fmaf(F, red_dq(dot4(Pc.q1, vq)), lgc.y);
                lgc.z = fmaf(F, red_dq(dot4(Pc.q2, vq)), lgc.z);
                lgc.w = fmaf(F, red_dq(dot4(Pc.q3, vq)), lgc.w);
            } else if (tid < DD) {
                out[((size_t)b * OO + o) * DD + tid] = finalv[tid] * F;
            }
        }
    }
}

extern "C" void kernel_launch(void* const* d_in, const int* in_sizes, int n_in,
                              void* d_out, int out_size, void* d_ws, size_t ws_size,
                              hipStream_t stream) {
    const float* inputs = (const float*)d_in[0];
    const float* W = (const float*)d_in[1];
    float* out = (float*)d_out;
    hipLaunchKernelGGL(capsule_nb1, dim3(GRID), dim3(NT), 0, stream,
                       inputs, W, out);
}